// Round 3
// baseline (7580.753 us; speedup 1.0000x reference)
//
#include <hip/hip_runtime.h>
#include <hip/hip_bf16.h>
#include <math.h>

#define SS 2048
#define BB 32
#define SBTOK (SS * BB)   // 65536 tokens

__device__ __forceinline__ float fsig(float x) { return 1.f / (1.f + __expf(-x)); }
__device__ __forceinline__ float ftanh(float x) {
  float e = __expf(-2.f * fabsf(x));
  return copysignf((1.f - e) / (1.f + e), x);
}

// ---------------- K0: zero scratch (state buffers) ----------------
__global__ __launch_bounds__(256) void zero_kernel(float* __restrict__ p, int n) {
  int i = blockIdx.x * 256 + threadIdx.x;
  if (i < n) p[i] = 0.f;
}

// ---------------- K1: char-LSTM features (1 step, h0=c0=0) ----------------
__global__ __launch_bounds__(256) void char_kernel(
    const int* __restrict__ seq, const float* __restrict__ cemb,
    const float* __restrict__ cWih, const float* __restrict__ cb,
    float* __restrict__ char_feat)
{
  int gid = blockIdx.x * 256 + threadIdx.x;
  int token = gid >> 6;          // t*B + b
  int u = gid & 63;
  int dir = u >> 5;
  int j = u & 31;
  int t = token >> 5;            // B = 32
  int b = token & 31;
  int sv = seq[b * SS + t] & 255;
  const float* ce = cemb + sv * 32;
  const float* Wd = cWih + dir * (128 * 32);
  float ai = cb[dir * 128 + j];
  float ag = cb[dir * 128 + 64 + j];
  float ao = cb[dir * 128 + 96 + j];
  #pragma unroll
  for (int k = 0; k < 32; ++k) {
    float cv = ce[k];
    ai = fmaf(cv, Wd[j * 32 + k], ai);
    ag = fmaf(cv, Wd[(64 + j) * 32 + k], ag);
    ao = fmaf(cv, Wd[(96 + j) * 32 + k], ao);
  }
  float c = fsig(ai) * ftanh(ag);
  float h = fsig(ao) * ftanh(c);
  char_feat[(size_t)token * 64 + dir * 32 + j] = h;
}

// ---------------- K2: input projection GEMM (per time-chunk) ----------------
// xg[dir][s_local][b][gate] = bias + sum_d A[t(dir,s_local)][d] * W[n][d]
// MODE 0: A = [wemb gather | char_feat], D=192.  MODE 1: A = h0 [SBTOK][256], D=256.
template<int MODE, int D>
__global__ __launch_bounds__(256) void proj_seg(
    const float* __restrict__ Asrc, const int* __restrict__ seq,
    const float* __restrict__ wemb, const float* __restrict__ W,
    const float* __restrict__ bias, float* __restrict__ xg,
    int Tc, int p)
{
  __shared__ float As[32][68];   // [k][m], padded
  __shared__ float Bs[32][68];   // [k][n]
  int tid = threadIdx.x;
  int tile_m = blockIdx.x * 64;  // over s_local*BB + b
  int tile_n = blockIdx.y * 64;  // over 1024 gates (dir = n>>9)
  int dir = tile_n >> 9;
  int tx = tid & 15, ty = tid >> 4;
  float acc[4][4] = {};
  for (int k0 = 0; k0 < D; k0 += 32) {
    #pragma unroll
    for (int l = tid; l < 2048; l += 256) {
      int row = l >> 5, k = l & 31;
      int m = tile_m + row;
      int s_local = m >> 5, b = m & 31;
      int t = dir ? (SS - 1 - p * Tc - s_local) : (p * Tc + s_local);
      int d = k0 + k;
      float av;
      if constexpr (MODE == 0) {
        if (d < 128) {
          int sv = seq[b * SS + t] & 255;
          av = wemb[sv * 128 + d];
        } else {
          av = Asrc[(size_t)(t * BB + b) * 64 + (d - 128)];
        }
      } else {
        av = Asrc[(size_t)(t * BB + b) * 256 + d];
      }
      As[k][row] = av;
      Bs[k][row] = W[(size_t)(tile_n + row) * D + d];
    }
    __syncthreads();
    #pragma unroll
    for (int k = 0; k < 32; ++k) {
      float4 av = *(const float4*)&As[k][ty * 4];
      float4 bv = *(const float4*)&Bs[k][tx * 4];
      float a[4] = {av.x, av.y, av.z, av.w};
      float bq[4] = {bv.x, bv.y, bv.z, bv.w};
      #pragma unroll
      for (int i = 0; i < 4; ++i)
        #pragma unroll
        for (int jj = 0; jj < 4; ++jj)
          acc[i][jj] = fmaf(a[i], bq[jj], acc[i][jj]);
    }
    __syncthreads();
  }
  #pragma unroll
  for (int i = 0; i < 4; ++i) {
    int m = tile_m + ty * 4 + i;
    int s_local = m >> 5, b = m & 31;
    #pragma unroll
    for (int jj = 0; jj < 4; ++jj) {
      int n = tile_n + tx * 4 + jj;
      xg[(((size_t)dir * Tc + s_local) * BB + b) * 512 + (n & 511)]
          = acc[i][jj] + bias[n];
    }
  }
}

// ---------------- K3: LSTM recurrence scan over one time-chunk ----------------
// one WG per (batch, dir); 512 threads, thread j owns gate j (Whh row in VGPRs).
// L==0: write h into full h0 [SBTOK][256]. L==1: write into chunk buf [2][Tc][B][128].
template<int L>
__global__ __launch_bounds__(512, 1) void scan_seg(
    const float* __restrict__ xg,   // [2][Tc][B][512]
    const float* __restrict__ Whh,  // [2][512][128]
    float* __restrict__ hout,
    float* __restrict__ hstate,     // [2][B][128]
    float* __restrict__ cstate,     // [2][B][128]
    int Tc, int p)
{
  int b = blockIdx.x & 31;
  int dir = blockIdx.x >> 5;
  int j = threadIdx.x;
  const float* xgd = xg + (size_t)dir * Tc * BB * 512;

  float4 w[32];
  const float4* wrow = (const float4*)(Whh + ((size_t)dir * 512 + j) * 128);
  #pragma unroll
  for (int k = 0; k < 32; ++k) w[k] = wrow[k];

  __shared__ alignas(16) float hl[128];
  __shared__ float gbuf[512];
  float c = 0.f;
  int sidx = (dir * 32 + b) * 128 + (j & 127);
  if (j < 128) { hl[j] = hstate[sidx]; c = cstate[sidx]; }
  __syncthreads();

  int tbase = dir ? (SS - 1 - p * Tc) : p * Tc;
  int dt = dir ? -1 : 1;

  float g0 = xgd[(size_t)b * 512 + j];
  float g1 = xgd[((size_t)BB + b) * 512 + j];

  for (int s = 0; s < Tc; ++s) {
    float g2 = 0.f;
    if (s + 2 < Tc) g2 = xgd[((size_t)(s + 2) * BB + b) * 512 + j];
    float acc = g0;
    const float4* h4 = (const float4*)hl;
    #pragma unroll
    for (int k = 0; k < 32; ++k) {
      float4 hv = h4[k];
      float4 wv = w[k];
      acc = fmaf(hv.x, wv.x, acc);
      acc = fmaf(hv.y, wv.y, acc);
      acc = fmaf(hv.z, wv.z, acc);
      acc = fmaf(hv.w, wv.w, acc);
    }
    gbuf[j] = acc;
    __syncthreads();
    if (j < 128) {
      float ig = gbuf[j], fg = gbuf[j + 128], gg = gbuf[j + 256], og = gbuf[j + 384];
      c = fsig(fg) * c + fsig(ig) * ftanh(gg);
      float h = fsig(og) * ftanh(c);
      hl[j] = h;
      if constexpr (L == 0) {
        int t = tbase + dt * s;
        hout[((size_t)t * BB + b) * 256 + (dir << 7) + j] = h;
      } else {
        hout[(((size_t)dir * Tc + s) * BB + b) * 128 + j] = h;
      }
    }
    __syncthreads();
    g0 = g1; g1 = g2;
  }
  if (j < 128) { hstate[sidx] = hl[j]; cstate[sidx] = c; }
}

// ---------------- K4: partial emissions from layer-1 h chunk ----------------
// em_part[dir][t][b][tag] = sum_j h1c[dir][s][b][j] * Wtag[tag][dir*128+j]
__global__ __launch_bounds__(256) void emis_seg(
    const float* __restrict__ h1c, const float* __restrict__ Wtag,
    float* __restrict__ em_part, int Tc, int p)
{
  int wv = blockIdx.x * 4 + (threadIdx.x >> 6);   // over (dir, s, b)
  int lane = threadIdx.x & 63;
  int b = wv & 31;
  int rest = wv >> 5;
  int dir = (rest >= Tc) ? 1 : 0;
  int s = rest - dir * Tc;
  float2 hv = ((const float2*)(h1c + (((size_t)dir * Tc + s) * BB + b) * 128))[lane];
  float pv[3];
  #pragma unroll
  for (int tg = 0; tg < 3; ++tg) {
    float2 wvv = ((const float2*)(Wtag + tg * 256 + dir * 128))[lane];
    pv[tg] = hv.x * wvv.x + hv.y * wvv.y;
  }
  #pragma unroll
  for (int off = 32; off > 0; off >>= 1) {
    pv[0] += __shfl_xor(pv[0], off);
    pv[1] += __shfl_xor(pv[1], off);
    pv[2] += __shfl_xor(pv[2], off);
  }
  if (lane == 0) {
    int t = dir ? (SS - 1 - p * Tc - s) : (p * Tc + s);
    size_t base = ((size_t)dir * SBTOK + (size_t)t * BB + b) * 3;
    em_part[base + 0] = pv[0];
    em_part[base + 1] = pv[1];
    em_part[base + 2] = pv[2];
  }
}

// ---------------- K5: CRF NLL ----------------
// em(t,b,j) = ef[(t*B+b)*3+j] + eb[...] + btag[j]
__global__ __launch_bounds__(128) void crf_kernel(
    const float* __restrict__ ef, const float* __restrict__ eb,
    const float* __restrict__ btag,
    const int* __restrict__ tags, const int* __restrict__ masks,
    const float* __restrict__ st, const float* __restrict__ et,
    const float* __restrict__ tr, float* __restrict__ out)
{
  int tid = threadIdx.x;
  int wave = tid >> 6;
  int lane = tid & 63;
  int bl = lane / 3;
  int j = lane - bl * 3;
  bool active = lane < 48;
  int b = wave * 16 + bl;
  float T[9];
  #pragma unroll
  for (int i = 0; i < 9; ++i) T[i] = tr[i];
  float b0 = btag[0], b1 = btag[1], b2 = btag[2];
  float btj = (j == 0) ? b0 : ((j == 1) ? b1 : b2);
  const int* tg = tags + (size_t)(active ? b : 0) * SS;
  const int* mk = masks + (size_t)(active ? b : 0) * SS;
  float a = -1e30f;
  float num = 0.f;
  int prev = 0, cnt = 0;
  if (active) {
    size_t e0 = (size_t)b * 3;
    a = st[j] + ef[e0 + j] + eb[e0 + j] + btj;
    prev = tg[0];
    if (j == 0) {
      float bp = (prev == 0) ? b0 : ((prev == 1) ? b1 : b2);
      num = st[prev] + ef[e0 + prev] + eb[e0 + prev] + bp;
    }
    cnt = (mk[0] != 0) ? 1 : 0;
  }
  int base = bl * 3;
  for (int t = 1; t < SS; ++t) {
    float e = 0.f, ect = 0.f;
    int m = 0, ct = 0;
    if (active) {
      size_t eo = ((size_t)t * BB + b) * 3;
      e = ef[eo + j] + eb[eo + j] + btj;
      m = mk[t];
      ct = tg[t];
      if (j == 0) {
        float bc = (ct == 0) ? b0 : ((ct == 1) ? b1 : b2);
        ect = ef[eo + ct] + eb[eo + ct] + bc;
      }
    }
    float a0 = __shfl(a, base + 0);
    float a1 = __shfl(a, base + 1);
    float a2 = __shfl(a, base + 2);
    float x0 = a0 + T[0 + j];
    float x1 = a1 + T[3 + j];
    float x2 = a2 + T[6 + j];
    float mx = fmaxf(fmaxf(x0, x1), x2);
    float na = mx + __logf(__expf(x0 - mx) + __expf(x1 - mx) + __expf(x2 - mx)) + e;
    if (m != 0) a = na;
    if (active && j == 0 && m != 0) num += T[prev * 3 + ct] + ect;
    if (active) { prev = ct; cnt += (m != 0); }
  }
  float a0 = __shfl(a, base + 0);
  float a1 = __shfl(a, base + 1);
  float a2 = __shfl(a, base + 2);
  __shared__ float rbuf[32];
  if (active && j == 0) {
    float x0 = a0 + et[0], x1 = a1 + et[1], x2 = a2 + et[2];
    float mx = fmaxf(fmaxf(x0, x1), x2);
    float den = mx + __logf(__expf(x0 - mx) + __expf(x1 - mx) + __expf(x2 - mx));
    int last = tg[cnt - 1];
    rbuf[b] = (num + et[last]) - den;
  }
  __syncthreads();
  if (tid == 0) {
    float s = 0.f;
    #pragma unroll
    for (int i = 0; i < 32; ++i) s += rbuf[i];
    out[0] = -s;
  }
}

extern "C" void kernel_launch(void* const* d_in, const int* in_sizes, int n_in,
                              void* d_out, int out_size, void* d_ws, size_t ws_size,
                              hipStream_t stream) {
  const int* seq    = (const int*)d_in[0];
  const int* tags   = (const int*)d_in[1];
  const int* masks  = (const int*)d_in[2];
  const float* wemb = (const float*)d_in[3];
  const float* cemb = (const float*)d_in[4];
  const float* cWih = (const float*)d_in[5];
  const float* cb   = (const float*)d_in[6];
  const float* l0Wih = (const float*)d_in[7];
  const float* l0Whh = (const float*)d_in[8];
  const float* l0b   = (const float*)d_in[9];
  const float* l1Wih = (const float*)d_in[10];
  const float* l1Whh = (const float*)d_in[11];
  const float* l1b   = (const float*)d_in[12];
  const float* Wtag  = (const float*)d_in[13];
  const float* btag  = (const float*)d_in[14];
  const float* st    = (const float*)d_in[15];
  const float* et    = (const float*)d_in[16];
  const float* tr    = (const float*)d_in[17];
  float* outp = (float*)d_out;

  // ---- choose time-chunk Tc so the workspace fits ws_size ----
  // floats: char 4.19M | xg Tc*32768 | h0 16.78M | h1chunk Tc*8192 | em_part 393216 | state 16384
  const size_t fixed_fl = 4194304ull + 16777216ull + 393216ull + 16384ull;
  int Tc = 64;
  const int cands[5] = {2048, 512, 256, 128, 64};
  for (int i = 0; i < 5; ++i) {
    size_t need = (fixed_fl + (size_t)cands[i] * 40960ull) * 4ull;
    if (need <= ws_size || i == 4) { Tc = cands[i]; if (need <= ws_size) break; }
  }
  int nphase = SS / Tc;

  float* ws = (float*)d_ws;
  float* char_feat = ws;                              // 4,194,304
  float* xg      = char_feat + 4194304;               // Tc*32768
  float* h0      = xg + (size_t)Tc * 32768;           // 16,777,216
  float* h1c     = h0 + 16777216;                     // Tc*8192
  float* em_part = h1c + (size_t)Tc * 8192;           // 393,216
  float* hstate  = em_part + 393216;                  // 8,192
  float* cstate  = hstate + 8192;                     // 8,192

  char_kernel<<<SBTOK * 64 / 256, 256, 0, stream>>>(seq, cemb, cWih, cb, char_feat);

  dim3 pg(Tc / 2, 16);
  // ---- layer 0 ----
  zero_kernel<<<64, 256, 0, stream>>>(hstate, 16384);
  for (int p = 0; p < nphase; ++p) {
    proj_seg<0, 192><<<pg, 256, 0, stream>>>(char_feat, seq, wemb, l0Wih, l0b, xg, Tc, p);
    scan_seg<0><<<64, 512, 0, stream>>>(xg, l0Whh, h0, hstate, cstate, Tc, p);
  }
  // ---- layer 1 ----
  zero_kernel<<<64, 256, 0, stream>>>(hstate, 16384);
  for (int p = 0; p < nphase; ++p) {
    proj_seg<1, 256><<<pg, 256, 0, stream>>>(h0, seq, wemb, l1Wih, l1b, xg, Tc, p);
    scan_seg<1><<<64, 512, 0, stream>>>(xg, l1Whh, h1c, hstate, cstate, Tc, p);
    emis_seg<<<Tc * 16, 256, 0, stream>>>(h1c, Wtag, em_part, Tc, p);
  }
  crf_kernel<<<1, 128, 0, stream>>>(em_part, em_part + (size_t)SBTOK * 3, btag,
                                    tags, masks, st, et, tr, outp);
}

// Round 4
// 6020.422 us; speedup vs baseline: 1.2592x; 1.2592x over previous
//
#include <hip/hip_runtime.h>
#include <hip/hip_bf16.h>
#include <math.h>

#define SS 2048
#define BB 32
#define SBTOK (SS * BB)   // 65536 tokens
#define NEG (-1e30f)

__device__ __forceinline__ float fsig(float x) { return 1.f / (1.f + __expf(-x)); }
__device__ __forceinline__ float ftanh(float x) {
  float e = __expf(-2.f * fabsf(x));
  return copysignf((1.f - e) / (1.f + e), x);
}
__device__ __forceinline__ float lse3(float x, float y, float z) {
  float mx = fmaxf(fmaxf(x, y), z);
  return mx + __logf(__expf(x - mx) + __expf(y - mx) + __expf(z - mx));
}

// ---------------- K0: zero scratch (state buffers) ----------------
__global__ __launch_bounds__(256) void zero_kernel(float* __restrict__ p, int n) {
  int i = blockIdx.x * 256 + threadIdx.x;
  if (i < n) p[i] = 0.f;
}

// ---------------- K1: char-LSTM features (1 step, h0=c0=0) ----------------
__global__ __launch_bounds__(256) void char_kernel(
    const int* __restrict__ seq, const float* __restrict__ cemb,
    const float* __restrict__ cWih, const float* __restrict__ cb,
    float* __restrict__ char_feat)
{
  int gid = blockIdx.x * 256 + threadIdx.x;
  int token = gid >> 6;          // t*B + b
  int u = gid & 63;
  int dir = u >> 5;
  int j = u & 31;
  int t = token >> 5;            // B = 32
  int b = token & 31;
  int sv = seq[b * SS + t] & 255;
  const float* ce = cemb + sv * 32;
  const float* Wd = cWih + dir * (128 * 32);
  float ai = cb[dir * 128 + j];
  float ag = cb[dir * 128 + 64 + j];
  float ao = cb[dir * 128 + 96 + j];
  #pragma unroll
  for (int k = 0; k < 32; ++k) {
    float cv = ce[k];
    ai = fmaf(cv, Wd[j * 32 + k], ai);
    ag = fmaf(cv, Wd[(64 + j) * 32 + k], ag);
    ao = fmaf(cv, Wd[(96 + j) * 32 + k], ao);
  }
  float c = fsig(ai) * ftanh(ag);
  float h = fsig(ao) * ftanh(c);
  char_feat[(size_t)token * 64 + dir * 32 + j] = h;
}

// ---------------- K2: input projection GEMM (128x64 tile) ----------------
template<int MODE, int D>
__global__ __launch_bounds__(256, 3) void proj_seg(
    const float* __restrict__ Asrc, const int* __restrict__ seq,
    const float* __restrict__ wemb, const float* __restrict__ W,
    const float* __restrict__ bias, float* __restrict__ xg,
    int Tc, int p)
{
  __shared__ float As[32][132];   // [k][m]
  __shared__ float Bs[32][68];    // [k][n]
  int tid = threadIdx.x;
  int tile_m = blockIdx.x * 128;  // over m = s_local*BB + b
  int tile_n = blockIdx.y * 64;   // over 1024 gates
  int dir = tile_n >> 9;
  int tx = tid & 15, ty = tid >> 4;
  float acc[8][4] = {};
  for (int k0 = 0; k0 < D; k0 += 32) {
    #pragma unroll
    for (int l = tid; l < 4096; l += 256) {
      int row = l >> 5, k = l & 31;
      int m = tile_m + row;
      int s_local = m >> 5, b = m & 31;
      int t = dir ? (SS - 1 - p * Tc - s_local) : (p * Tc + s_local);
      int d = k0 + k;
      float av;
      if constexpr (MODE == 0) {
        if (d < 128) {
          int sv = seq[b * SS + t] & 255;
          av = wemb[sv * 128 + d];
        } else {
          av = Asrc[(size_t)(t * BB + b) * 64 + (d - 128)];
        }
      } else {
        av = Asrc[(size_t)(t * BB + b) * 256 + d];
      }
      As[k][row] = av;
    }
    #pragma unroll
    for (int l = tid; l < 2048; l += 256) {
      int row = l >> 5, k = l & 31;
      Bs[k][row] = W[(size_t)(tile_n + row) * D + (k0 + k)];
    }
    __syncthreads();
    #pragma unroll
    for (int k = 0; k < 32; ++k) {
      float4 av0 = *(const float4*)&As[k][ty * 8];
      float4 av1 = *(const float4*)&As[k][ty * 8 + 4];
      float4 bv = *(const float4*)&Bs[k][tx * 4];
      float a[8] = {av0.x, av0.y, av0.z, av0.w, av1.x, av1.y, av1.z, av1.w};
      float bq[4] = {bv.x, bv.y, bv.z, bv.w};
      #pragma unroll
      for (int i = 0; i < 8; ++i)
        #pragma unroll
        for (int jj = 0; jj < 4; ++jj)
          acc[i][jj] = fmaf(a[i], bq[jj], acc[i][jj]);
    }
    __syncthreads();
  }
  int nbase = tile_n + tx * 4;
  float4 bb4 = *(const float4*)&bias[nbase];
  #pragma unroll
  for (int i = 0; i < 8; ++i) {
    int m = tile_m + ty * 8 + i;
    int s_local = m >> 5, b = m & 31;
    float4 o;
    o.x = acc[i][0] + bb4.x; o.y = acc[i][1] + bb4.y;
    o.z = acc[i][2] + bb4.z; o.w = acc[i][3] + bb4.w;
    *(float4*)&xg[(((size_t)dir * Tc + s_local) * BB + b) * 512 + (nbase & 511)] = o;
  }
}

// ---------------- K3: LSTM recurrence scan (k-quarter split) ----------------
// 512 threads: wave w, lane l: r = w*16 + (l&15), q = l>>4.
// Thread computes partial i,f,g,o for row r over k in [32q, 32q+32).
#define HIDX(k) ((((k) >> 5) * 36) + ((k) & 31))
template<int L>
__global__ __launch_bounds__(512, 2) void scan_seg(
    const float* __restrict__ xg,   // [2][Tc][B][512]
    const float* __restrict__ Whh,  // [2][512][128]
    float* __restrict__ hout,
    float* __restrict__ hstate,     // [2][B][128]
    float* __restrict__ cstate,     // [2][B][128]
    int Tc, int p)
{
  int b = blockIdx.x & 31;
  int dir = blockIdx.x >> 5;
  int tid = threadIdx.x;
  int w = tid >> 6;
  int lane = tid & 63;
  int r = w * 16 + (lane & 15);
  int q = lane >> 4;
  bool q0 = (q == 0);
  const float* xgd = xg + (size_t)dir * Tc * BB * 512;

  // weights: 4 gate-rows (r, r+128, r+256, r+384), k-slice [32q, 32q+32)
  float4 W[4][8];
  #pragma unroll
  for (int g = 0; g < 4; ++g) {
    const float4* wr = (const float4*)(Whh + ((size_t)dir * 512 + g * 128 + r) * 128 + q * 32);
    #pragma unroll
    for (int e = 0; e < 8; ++e) W[g][e] = wr[e];
  }

  __shared__ alignas(16) float hl[2][144];
  int sidx = (dir * 32 + b) * 128 + r;
  float c = cstate[sidx];
  if (q0) hl[0][HIDX(r)] = hstate[sidx];
  __syncthreads();

  int tbase = dir ? (SS - 1 - p * Tc) : p * Tc;
  int dt = dir ? -1 : 1;

  float xc[4] = {0.f, 0.f, 0.f, 0.f};
  if (q0) {
    #pragma unroll
    for (int g = 0; g < 4; ++g) xc[g] = xgd[(size_t)b * 512 + g * 128 + r];
  }

  int cur = 0;
  for (int s = 0; s < Tc; ++s) {
    float xn[4] = {0.f, 0.f, 0.f, 0.f};
    if (q0 && s + 1 < Tc) {
      #pragma unroll
      for (int g = 0; g < 4; ++g)
        xn[g] = xgd[((size_t)(s + 1) * BB + b) * 512 + g * 128 + r];
    }
    float acc0 = xc[0], acc1 = xc[1], acc2 = xc[2], acc3 = xc[3];
    const float4* h4 = (const float4*)&hl[cur][q * 36];
    #pragma unroll
    for (int e = 0; e < 8; ++e) {
      float4 hv = h4[e];
      acc0 = fmaf(hv.x, W[0][e].x, acc0); acc0 = fmaf(hv.y, W[0][e].y, acc0);
      acc0 = fmaf(hv.z, W[0][e].z, acc0); acc0 = fmaf(hv.w, W[0][e].w, acc0);
      acc1 = fmaf(hv.x, W[1][e].x, acc1); acc1 = fmaf(hv.y, W[1][e].y, acc1);
      acc1 = fmaf(hv.z, W[1][e].z, acc1); acc1 = fmaf(hv.w, W[1][e].w, acc1);
      acc2 = fmaf(hv.x, W[2][e].x, acc2); acc2 = fmaf(hv.y, W[2][e].y, acc2);
      acc2 = fmaf(hv.z, W[2][e].z, acc2); acc2 = fmaf(hv.w, W[2][e].w, acc2);
      acc3 = fmaf(hv.x, W[3][e].x, acc3); acc3 = fmaf(hv.y, W[3][e].y, acc3);
      acc3 = fmaf(hv.z, W[3][e].z, acc3); acc3 = fmaf(hv.w, W[3][e].w, acc3);
    }
    // reduce partials across q (lane bits 4,5)
    acc0 += __shfl_xor(acc0, 16); acc0 += __shfl_xor(acc0, 32);
    acc1 += __shfl_xor(acc1, 16); acc1 += __shfl_xor(acc1, 32);
    acc2 += __shfl_xor(acc2, 16); acc2 += __shfl_xor(acc2, 32);
    acc3 += __shfl_xor(acc3, 16); acc3 += __shfl_xor(acc3, 32);
    // activation (redundant across q, deterministic)
    c = fsig(acc1) * c + fsig(acc0) * ftanh(acc2);
    float h = fsig(acc3) * ftanh(c);
    int nxt = cur ^ 1;
    if (q0) {
      hl[nxt][HIDX(r)] = h;
      if constexpr (L == 0) {
        int t = tbase + dt * s;
        hout[((size_t)t * BB + b) * 256 + (dir << 7) + r] = h;
      } else {
        hout[(((size_t)dir * Tc + s) * BB + b) * 128 + r] = h;
      }
    }
    __syncthreads();
    cur = nxt;
    xc[0] = xn[0]; xc[1] = xn[1]; xc[2] = xn[2]; xc[3] = xn[3];
  }
  if (q0) { hstate[sidx] = hl[cur][HIDX(r)]; cstate[sidx] = c; }
}

// ---------------- K4: partial emissions from layer-1 h chunk ----------------
__global__ __launch_bounds__(256) void emis_seg(
    const float* __restrict__ h1c, const float* __restrict__ Wtag,
    float* __restrict__ em_part, int Tc, int p)
{
  int wv = blockIdx.x * 4 + (threadIdx.x >> 6);   // over (dir, s, b)
  int lane = threadIdx.x & 63;
  int b = wv & 31;
  int rest = wv >> 5;
  int dir = (rest >= Tc) ? 1 : 0;
  int s = rest - dir * Tc;
  float2 hv = ((const float2*)(h1c + (((size_t)dir * Tc + s) * BB + b) * 128))[lane];
  float pv[3];
  #pragma unroll
  for (int tg = 0; tg < 3; ++tg) {
    float2 wvv = ((const float2*)(Wtag + tg * 256 + dir * 128))[lane];
    pv[tg] = hv.x * wvv.x + hv.y * wvv.y;
  }
  #pragma unroll
  for (int off = 32; off > 0; off >>= 1) {
    pv[0] += __shfl_xor(pv[0], off);
    pv[1] += __shfl_xor(pv[1], off);
    pv[2] += __shfl_xor(pv[2], off);
  }
  if (lane == 0) {
    int t = dir ? (SS - 1 - p * Tc - s) : (p * Tc + s);
    size_t base = ((size_t)dir * SBTOK + (size_t)t * BB + b) * 3;
    em_part[base + 0] = pv[0];
    em_part[base + 1] = pv[1];
    em_part[base + 2] = pv[2];
  }
}

// ---------------- K5a: CRF chunk transfer matrices ----------------
// 512 segments = 32 batches x 16 chunks of 128 steps (last 127).
// block = one batch (256 thr = 16 groups of 16 lanes); group = chunk.
__global__ __launch_bounds__(256) void crf_seg(
    const float* __restrict__ ef, const float* __restrict__ eb,
    const float* __restrict__ btag, const float* __restrict__ masks,
    const float* __restrict__ dummy, const float* __restrict__ tr_,
    float* __restrict__ segM)
{
  int b = blockIdx.x;
  int tid = threadIdx.x;
  int ch = tid >> 4;
  int lane = tid & 63;
  int jj = tid & 15;
  int base = lane & 48;
  int col = (jj < 3) ? jj : 0;
  float T0 = tr_[0 * 3 + col], T1 = tr_[1 * 3 + col], T2 = tr_[2 * 3 + col];
  float btj = btag[col];
  const int* mk = (const int*)masks + (size_t)b * SS;
  int t0 = 1 + ch * 128;
  int len = (ch == 15) ? 127 : 128;
  float S0, S1, S2;
  {
    size_t eo = ((size_t)t0 * BB + b) * 3;
    float e = ef[eo + col] + eb[eo + col] + btj;
    if (mk[t0] != 0) { S0 = T0 + e; S1 = T1 + e; S2 = T2 + e; }
    else { S0 = (col == 0) ? 0.f : NEG; S1 = (col == 1) ? 0.f : NEG; S2 = (col == 2) ? 0.f : NEG; }
  }
  for (int i = 1; i < len; ++i) {
    int t = t0 + i;
    size_t eo = ((size_t)t * BB + b) * 3;
    float e = ef[eo + col] + eb[eo + col] + btj;
    int m = mk[t];
    float M0 = T0 + e, M1 = T1 + e, M2 = T2 + e;
    float r00 = __shfl(S0, base + 0), r01 = __shfl(S0, base + 1), r02 = __shfl(S0, base + 2);
    float r10 = __shfl(S1, base + 0), r11 = __shfl(S1, base + 1), r12 = __shfl(S1, base + 2);
    float r20 = __shfl(S2, base + 0), r21 = __shfl(S2, base + 1), r22 = __shfl(S2, base + 2);
    if (m != 0) {
      S0 = lse3(r00 + M0, r01 + M1, r02 + M2);
      S1 = lse3(r10 + M0, r11 + M1, r12 + M2);
      S2 = lse3(r20 + M0, r21 + M1, r22 + M2);
    }
  }
  if (jj < 3) {
    float* o = segM + ((size_t)b * 16 + ch) * 9;
    o[0 * 3 + jj] = S0;
    o[1 * 3 + jj] = S1;
    o[2 * 3 + jj] = S2;
  }
}

// ---------------- K5b: gold path score (parallel over t) ----------------
__global__ __launch_bounds__(64) void crf_num(
    const float* __restrict__ ef, const float* __restrict__ eb,
    const float* __restrict__ btag, const int* __restrict__ tags,
    const int* __restrict__ masks, const float* __restrict__ st,
    const float* __restrict__ et, const float* __restrict__ tr_,
    float* __restrict__ numb)
{
  int b = blockIdx.x;
  int lane = threadIdx.x;
  float T[9];
  #pragma unroll
  for (int i = 0; i < 9; ++i) T[i] = tr_[i];
  float b0 = btag[0], b1 = btag[1], b2 = btag[2];
  const int* tg = tags + (size_t)b * SS;
  const int* mk = masks + (size_t)b * SS;
  float part = 0.f;
  int cnt = 0;
  for (int t = lane; t < SS; t += 64) {
    int m = mk[t];
    cnt += (m != 0);
    if (t > 0 && m != 0) {
      int ct = tg[t], pv = tg[t - 1];
      size_t eo = ((size_t)t * BB + b) * 3;
      float bc = (ct == 0) ? b0 : ((ct == 1) ? b1 : b2);
      part += T[pv * 3 + ct] + ef[eo + ct] + eb[eo + ct] + bc;
    }
  }
  #pragma unroll
  for (int off = 32; off > 0; off >>= 1) {
    part += __shfl_xor(part, off);
    cnt += __shfl_xor(cnt, off);
  }
  if (lane == 0) {
    int tg0 = tg[0];
    float bc = (tg0 == 0) ? b0 : ((tg0 == 1) ? b1 : b2);
    float num = part + st[tg0] + ef[b * 3 + tg0] + eb[b * 3 + tg0] + bc;
    int last = tg[cnt - 1];
    num += et[last];
    numb[b] = num;
  }
}

// ---------------- K5c: combine chunks, partition, final NLL ----------------
__global__ __launch_bounds__(512) void crf_fin(
    const float* __restrict__ segM, const float* __restrict__ numb,
    const float* __restrict__ ef, const float* __restrict__ eb,
    const float* __restrict__ btag, const float* __restrict__ st,
    const float* __restrict__ et, float* __restrict__ out)
{
  int tid = threadIdx.x;
  int b = tid >> 4;
  int lane = tid & 63;
  int jj = tid & 15;
  int base = lane & 48;
  int col = (jj < 3) ? jj : 0;
  const float* sm = segM + (size_t)b * 16 * 9;
  float S0 = sm[0 * 3 + col], S1 = sm[1 * 3 + col], S2 = sm[2 * 3 + col];
  for (int ch = 1; ch < 16; ++ch) {
    float M0 = sm[ch * 9 + 0 * 3 + col];
    float M1 = sm[ch * 9 + 1 * 3 + col];
    float M2 = sm[ch * 9 + 2 * 3 + col];
    float r00 = __shfl(S0, base + 0), r01 = __shfl(S0, base + 1), r02 = __shfl(S0, base + 2);
    float r10 = __shfl(S1, base + 0), r11 = __shfl(S1, base + 1), r12 = __shfl(S1, base + 2);
    float r20 = __shfl(S2, base + 0), r21 = __shfl(S2, base + 1), r22 = __shfl(S2, base + 2);
    S0 = lse3(r00 + M0, r01 + M1, r02 + M2);
    S1 = lse3(r10 + M0, r11 + M1, r12 + M2);
    S2 = lse3(r20 + M0, r21 + M1, r22 + M2);
  }
  // a0[k] = st[k] + em0[k]
  float A0 = st[0] + ef[b * 3 + 0] + eb[b * 3 + 0] + btag[0];
  float A1 = st[1] + ef[b * 3 + 1] + eb[b * 3 + 1] + btag[1];
  float A2 = st[2] + ef[b * 3 + 2] + eb[b * 3 + 2] + btag[2];
  float alpha = lse3(A0 + S0, A1 + S1, A2 + S2);   // column jj
  float v = alpha + et[col];
  float v0 = __shfl(v, base + 0), v1 = __shfl(v, base + 1), v2 = __shfl(v, base + 2);
  float den = lse3(v0, v1, v2);
  __shared__ float rbuf[32];
  if (jj == 0) rbuf[b] = numb[b] - den;
  __syncthreads();
  if (tid == 0) {
    float s = 0.f;
    #pragma unroll
    for (int i = 0; i < 32; ++i) s += rbuf[i];
    out[0] = -s;
  }
}

extern "C" void kernel_launch(void* const* d_in, const int* in_sizes, int n_in,
                              void* d_out, int out_size, void* d_ws, size_t ws_size,
                              hipStream_t stream) {
  const int* seq    = (const int*)d_in[0];
  const int* tags   = (const int*)d_in[1];
  const int* masks  = (const int*)d_in[2];
  const float* wemb = (const float*)d_in[3];
  const float* cemb = (const float*)d_in[4];
  const float* cWih = (const float*)d_in[5];
  const float* cb   = (const float*)d_in[6];
  const float* l0Wih = (const float*)d_in[7];
  const float* l0Whh = (const float*)d_in[8];
  const float* l0b   = (const float*)d_in[9];
  const float* l1Wih = (const float*)d_in[10];
  const float* l1Whh = (const float*)d_in[11];
  const float* l1b   = (const float*)d_in[12];
  const float* Wtag  = (const float*)d_in[13];
  const float* btag  = (const float*)d_in[14];
  const float* st    = (const float*)d_in[15];
  const float* et    = (const float*)d_in[16];
  const float* tr    = (const float*)d_in[17];
  float* outp = (float*)d_out;

  // ---- choose time-chunk Tc so the workspace fits ws_size ----
  const size_t fixed_fl = 4194304ull + 16777216ull + 393216ull + 16384ull + 8192ull;
  int Tc = 64;
  const int cands[5] = {2048, 512, 256, 128, 64};
  for (int i = 0; i < 5; ++i) {
    size_t need = (fixed_fl + (size_t)cands[i] * 40960ull) * 4ull;
    if (need <= ws_size || i == 4) { Tc = cands[i]; if (need <= ws_size) break; }
  }
  int nphase = SS / Tc;

  float* ws = (float*)d_ws;
  float* char_feat = ws;                              // 4,194,304
  float* xg      = char_feat + 4194304;               // Tc*32768
  float* h0      = xg + (size_t)Tc * 32768;           // 16,777,216
  float* h1c     = h0 + 16777216;                     // Tc*8192
  float* em_part = h1c + (size_t)Tc * 8192;           // 393,216
  float* hstate  = em_part + 393216;                  // 8,192
  float* cstate  = hstate + 8192;                     // 8,192
  float* segM    = cstate + 8192;                     // 4,608
  float* numb    = segM + 4608;                       // 32

  char_kernel<<<SBTOK * 64 / 256, 256, 0, stream>>>(seq, cemb, cWih, cb, char_feat);

  dim3 pg(Tc / 4, 16);
  // ---- layer 0 ----
  zero_kernel<<<64, 256, 0, stream>>>(hstate, 16384);
  for (int p = 0; p < nphase; ++p) {
    proj_seg<0, 192><<<pg, 256, 0, stream>>>(char_feat, seq, wemb, l0Wih, l0b, xg, Tc, p);
    scan_seg<0><<<64, 512, 0, stream>>>(xg, l0Whh, h0, hstate, cstate, Tc, p);
  }
  // ---- layer 1 ----
  zero_kernel<<<64, 256, 0, stream>>>(hstate, 16384);
  for (int p = 0; p < nphase; ++p) {
    proj_seg<1, 256><<<pg, 256, 0, stream>>>(h0, seq, wemb, l1Wih, l1b, xg, Tc, p);
    scan_seg<1><<<64, 512, 0, stream>>>(xg, l1Whh, h1c, hstate, cstate, Tc, p);
    emis_seg<<<Tc * 16, 256, 0, stream>>>(h1c, Wtag, em_part, Tc, p);
  }
  const float* ef = em_part;
  const float* eb = em_part + (size_t)SBTOK * 3;
  crf_seg<<<32, 256, 0, stream>>>(ef, eb, btag, (const float*)masks, nullptr, tr, segM);
  crf_num<<<32, 64, 0, stream>>>(ef, eb, btag, tags, masks, st, et, tr, numb);
  crf_fin<<<1, 512, 0, stream>>>(segM, numb, ef, eb, btag, st, et, outp);
}

// Round 5
// 4957.277 us; speedup vs baseline: 1.5292x; 1.2145x over previous
//
#include <hip/hip_runtime.h>
#include <hip/hip_bf16.h>
#include <math.h>

#define SS 2048
#define BB 32
#define SBTOK (SS * BB)   // 65536 tokens
#define NEG (-1e30f)

typedef _Float16 half2_t __attribute__((ext_vector_type(2)));

#if __has_builtin(__builtin_amdgcn_fdot2)
#define DOT2(a, b, c) __builtin_amdgcn_fdot2((a), (b), (c), false)
#else
#define DOT2(a, b, c) fmaf((float)(a).x, (float)(b).x, fmaf((float)(a).y, (float)(b).y, (c)))
#endif

__device__ __forceinline__ half2_t f2h2(float f) {
  union { float f; half2_t h; } u; u.f = f; return u.h;
}

__device__ __forceinline__ float fsig(float x) { return 1.f / (1.f + __expf(-x)); }
__device__ __forceinline__ float ftanh(float x) {
  float e = __expf(-2.f * fabsf(x));
  return copysignf((1.f - e) / (1.f + e), x);
}
__device__ __forceinline__ float lse3(float x, float y, float z) {
  float mx = fmaxf(fmaxf(x, y), z);
  return mx + __logf(__expf(x - mx) + __expf(y - mx) + __expf(z - mx));
}

// ---------------- K0: zero scratch (state buffers) ----------------
__global__ __launch_bounds__(256) void zero_kernel(float* __restrict__ p, int n) {
  int i = blockIdx.x * 256 + threadIdx.x;
  if (i < n) p[i] = 0.f;
}

// ---------------- K1: char-LSTM features (1 step, h0=c0=0) ----------------
__global__ __launch_bounds__(256) void char_kernel(
    const int* __restrict__ seq, const float* __restrict__ cemb,
    const float* __restrict__ cWih, const float* __restrict__ cb,
    float* __restrict__ char_feat)
{
  int gid = blockIdx.x * 256 + threadIdx.x;
  int token = gid >> 6;          // t*B + b
  int u = gid & 63;
  int dir = u >> 5;
  int j = u & 31;
  int t = token >> 5;            // B = 32
  int b = token & 31;
  int sv = seq[b * SS + t] & 255;
  const float* ce = cemb + sv * 32;
  const float* Wd = cWih + dir * (128 * 32);
  float ai = cb[dir * 128 + j];
  float ag = cb[dir * 128 + 64 + j];
  float ao = cb[dir * 128 + 96 + j];
  #pragma unroll
  for (int k = 0; k < 32; ++k) {
    float cv = ce[k];
    ai = fmaf(cv, Wd[j * 32 + k], ai);
    ag = fmaf(cv, Wd[(64 + j) * 32 + k], ag);
    ao = fmaf(cv, Wd[(96 + j) * 32 + k], ao);
  }
  float c = fsig(ai) * ftanh(ag);
  float h = fsig(ao) * ftanh(c);
  char_feat[(size_t)token * 64 + dir * 32 + j] = h;
}

// ---------------- K2: input projection GEMM (128x64 tile) ----------------
template<int MODE, int D>
__global__ __launch_bounds__(256, 3) void proj_seg(
    const float* __restrict__ Asrc, const int* __restrict__ seq,
    const float* __restrict__ wemb, const float* __restrict__ W,
    const float* __restrict__ bias, float* __restrict__ xg,
    int Tc, int p)
{
  __shared__ float As[32][132];   // [k][m]
  __shared__ float Bs[32][68];    // [k][n]
  int tid = threadIdx.x;
  int tile_m = blockIdx.x * 128;  // over m = s_local*BB + b
  int tile_n = blockIdx.y * 64;   // over 1024 gates
  int dir = tile_n >> 9;
  int tx = tid & 15, ty = tid >> 4;
  float acc[8][4] = {};
  for (int k0 = 0; k0 < D; k0 += 32) {
    #pragma unroll
    for (int l = tid; l < 4096; l += 256) {
      int row = l >> 5, k = l & 31;
      int m = tile_m + row;
      int s_local = m >> 5, b = m & 31;
      int t = dir ? (SS - 1 - p * Tc - s_local) : (p * Tc + s_local);
      int d = k0 + k;
      float av;
      if constexpr (MODE == 0) {
        if (d < 128) {
          int sv = seq[b * SS + t] & 255;
          av = wemb[sv * 128 + d];
        } else {
          av = Asrc[(size_t)(t * BB + b) * 64 + (d - 128)];
        }
      } else {
        av = Asrc[(size_t)(t * BB + b) * 256 + d];
      }
      As[k][row] = av;
    }
    #pragma unroll
    for (int l = tid; l < 2048; l += 256) {
      int row = l >> 5, k = l & 31;
      Bs[k][row] = W[(size_t)(tile_n + row) * D + (k0 + k)];
    }
    __syncthreads();
    #pragma unroll
    for (int k = 0; k < 32; ++k) {
      float4 av0 = *(const float4*)&As[k][ty * 8];
      float4 av1 = *(const float4*)&As[k][ty * 8 + 4];
      float4 bv = *(const float4*)&Bs[k][tx * 4];
      float a[8] = {av0.x, av0.y, av0.z, av0.w, av1.x, av1.y, av1.z, av1.w};
      float bq[4] = {bv.x, bv.y, bv.z, bv.w};
      #pragma unroll
      for (int i = 0; i < 8; ++i)
        #pragma unroll
        for (int jj = 0; jj < 4; ++jj)
          acc[i][jj] = fmaf(a[i], bq[jj], acc[i][jj]);
    }
    __syncthreads();
  }
  int nbase = tile_n + tx * 4;
  float4 bb4 = *(const float4*)&bias[nbase];
  #pragma unroll
  for (int i = 0; i < 8; ++i) {
    int m = tile_m + ty * 8 + i;
    int s_local = m >> 5, b = m & 31;
    float4 o;
    o.x = acc[i][0] + bb4.x; o.y = acc[i][1] + bb4.y;
    o.z = acc[i][2] + bb4.z; o.w = acc[i][3] + bb4.w;
    *(float4*)&xg[(((size_t)dir * Tc + s_local) * BB + b) * 512 + (nbase & 511)] = o;
  }
}

// ---------------- K3: LSTM recurrence scan (f16 dot2, k-quarter split) ----------------
// 512 threads: wave w, lane l: r = w*16 + (l&15), q = l>>4.
// Thread computes partial i,f,g,o for row r over k in [32q, 32q+32) via v_dot2_f32_f16.
// Whh held as half2 in 64 VGPRs; h stored packed-f16 in LDS (broadcast reads).
template<int L>
__global__ __launch_bounds__(512, 1) void scan_seg(
    const float* __restrict__ xg,   // [2][Tc][B][512] f32
    const float* __restrict__ Whh,  // [2][512][128] f32
    float* __restrict__ hout,
    float* __restrict__ hstate,     // [2][B][128]
    float* __restrict__ cstate,     // [2][B][128]
    int Tc, int p)
{
  int b = blockIdx.x & 31;
  int dir = blockIdx.x >> 5;
  int tid = threadIdx.x;
  int w = tid >> 6;
  int lane = tid & 63;
  int r = w * 16 + (lane & 15);
  int q = lane >> 4;
  bool q0 = (q == 0);
  const float* xgd = xg + (size_t)dir * Tc * BB * 512;

  // weights: 4 gate-rows (r, r+128g), k-slice [32q,32q+32), converted to half2 (64 VGPR)
  half2_t W[4][16];
  #pragma unroll
  for (int g = 0; g < 4; ++g) {
    const float4* wr = (const float4*)(Whh + ((size_t)dir * 512 + g * 128 + r) * 128 + q * 32);
    #pragma unroll
    for (int e2 = 0; e2 < 8; ++e2) {
      float4 v = wr[e2];
      half2_t lo, hi;
      lo.x = (_Float16)v.x; lo.y = (_Float16)v.y;
      hi.x = (_Float16)v.z; hi.y = (_Float16)v.w;
      W[g][2 * e2] = lo; W[g][2 * e2 + 1] = hi;
    }
  }

  __shared__ alignas(16) _Float16 hl[2][128];
  int sidx = (dir * 32 + b) * 128 + r;
  float c = cstate[sidx];
  if (q0) hl[0][r] = (_Float16)hstate[sidx];
  __syncthreads();

  int tbase = dir ? (SS - 1 - p * Tc) : p * Tc;
  int dt = dir ? -1 : 1;

  float xc[4] = {0.f, 0.f, 0.f, 0.f};
  if (q0) {
    #pragma unroll
    for (int g = 0; g < 4; ++g) xc[g] = xgd[(size_t)b * 512 + g * 128 + r];
  }

  int cur = 0;
  for (int s = 0; s < Tc; ++s) {
    float xn[4] = {0.f, 0.f, 0.f, 0.f};
    if (q0 && s + 1 < Tc) {
      #pragma unroll
      for (int g = 0; g < 4; ++g)
        xn[g] = xgd[((size_t)(s + 1) * BB + b) * 512 + g * 128 + r];
    }
    float acc0 = xc[0], acc1 = xc[1], acc2 = xc[2], acc3 = xc[3];
    const float4* h4 = (const float4*)&hl[cur][q * 32];   // 4 x 16B = 32 f16
    #pragma unroll
    for (int e = 0; e < 4; ++e) {
      float4 hv = h4[e];
      half2_t p0 = f2h2(hv.x), p1 = f2h2(hv.y), p2 = f2h2(hv.z), p3 = f2h2(hv.w);
      acc0 = DOT2(p0, W[0][4 * e + 0], acc0);
      acc0 = DOT2(p1, W[0][4 * e + 1], acc0);
      acc0 = DOT2(p2, W[0][4 * e + 2], acc0);
      acc0 = DOT2(p3, W[0][4 * e + 3], acc0);
      acc1 = DOT2(p0, W[1][4 * e + 0], acc1);
      acc1 = DOT2(p1, W[1][4 * e + 1], acc1);
      acc1 = DOT2(p2, W[1][4 * e + 2], acc1);
      acc1 = DOT2(p3, W[1][4 * e + 3], acc1);
      acc2 = DOT2(p0, W[2][4 * e + 0], acc2);
      acc2 = DOT2(p1, W[2][4 * e + 1], acc2);
      acc2 = DOT2(p2, W[2][4 * e + 2], acc2);
      acc2 = DOT2(p3, W[2][4 * e + 3], acc2);
      acc3 = DOT2(p0, W[3][4 * e + 0], acc3);
      acc3 = DOT2(p1, W[3][4 * e + 1], acc3);
      acc3 = DOT2(p2, W[3][4 * e + 2], acc3);
      acc3 = DOT2(p3, W[3][4 * e + 3], acc3);
    }
    // reduce partials across q (lane bits 4,5)
    acc0 += __shfl_xor(acc0, 16); acc0 += __shfl_xor(acc0, 32);
    acc1 += __shfl_xor(acc1, 16); acc1 += __shfl_xor(acc1, 32);
    acc2 += __shfl_xor(acc2, 16); acc2 += __shfl_xor(acc2, 32);
    acc3 += __shfl_xor(acc3, 16); acc3 += __shfl_xor(acc3, 32);
    // activation (redundant across q, deterministic)
    c = fsig(acc1) * c + fsig(acc0) * ftanh(acc2);
    float h = fsig(acc3) * ftanh(c);
    int nxt = cur ^ 1;
    if (q0) {
      hl[nxt][r] = (_Float16)h;
      if constexpr (L == 0) {
        int t = tbase + dt * s;
        hout[((size_t)t * BB + b) * 256 + (dir << 7) + r] = h;
      } else {
        hout[(((size_t)dir * Tc + s) * BB + b) * 128 + r] = h;
      }
    }
    __syncthreads();
    cur = nxt;
    xc[0] = xn[0]; xc[1] = xn[1]; xc[2] = xn[2]; xc[3] = xn[3];
  }
  if (q0) { hstate[sidx] = (float)hl[cur][r]; cstate[sidx] = c; }
}

// ---------------- K4: partial emissions from layer-1 h chunk ----------------
__global__ __launch_bounds__(256) void emis_seg(
    const float* __restrict__ h1c, const float* __restrict__ Wtag,
    float* __restrict__ em_part, int Tc, int p)
{
  int wv = blockIdx.x * 4 + (threadIdx.x >> 6);   // over (dir, s, b)
  int lane = threadIdx.x & 63;
  int b = wv & 31;
  int rest = wv >> 5;
  int dir = (rest >= Tc) ? 1 : 0;
  int s = rest - dir * Tc;
  float2 hv = ((const float2*)(h1c + (((size_t)dir * Tc + s) * BB + b) * 128))[lane];
  float pv[3];
  #pragma unroll
  for (int tg = 0; tg < 3; ++tg) {
    float2 wvv = ((const float2*)(Wtag + tg * 256 + dir * 128))[lane];
    pv[tg] = hv.x * wvv.x + hv.y * wvv.y;
  }
  #pragma unroll
  for (int off = 32; off > 0; off >>= 1) {
    pv[0] += __shfl_xor(pv[0], off);
    pv[1] += __shfl_xor(pv[1], off);
    pv[2] += __shfl_xor(pv[2], off);
  }
  if (lane == 0) {
    int t = dir ? (SS - 1 - p * Tc - s) : (p * Tc + s);
    size_t base = ((size_t)dir * SBTOK + (size_t)t * BB + b) * 3;
    em_part[base + 0] = pv[0];
    em_part[base + 1] = pv[1];
    em_part[base + 2] = pv[2];
  }
}

// ---------------- K5a: CRF chunk transfer matrices ----------------
__global__ __launch_bounds__(256) void crf_seg(
    const float* __restrict__ ef, const float* __restrict__ eb,
    const float* __restrict__ btag, const float* __restrict__ masks,
    const float* __restrict__ dummy, const float* __restrict__ tr_,
    float* __restrict__ segM)
{
  int b = blockIdx.x;
  int tid = threadIdx.x;
  int ch = tid >> 4;
  int lane = tid & 63;
  int jj = tid & 15;
  int base = lane & 48;
  int col = (jj < 3) ? jj : 0;
  float T0 = tr_[0 * 3 + col], T1 = tr_[1 * 3 + col], T2 = tr_[2 * 3 + col];
  float btj = btag[col];
  const int* mk = (const int*)masks + (size_t)b * SS;
  int t0 = 1 + ch * 128;
  int len = (ch == 15) ? 127 : 128;
  float S0, S1, S2;
  {
    size_t eo = ((size_t)t0 * BB + b) * 3;
    float e = ef[eo + col] + eb[eo + col] + btj;
    if (mk[t0] != 0) { S0 = T0 + e; S1 = T1 + e; S2 = T2 + e; }
    else { S0 = (col == 0) ? 0.f : NEG; S1 = (col == 1) ? 0.f : NEG; S2 = (col == 2) ? 0.f : NEG; }
  }
  for (int i = 1; i < len; ++i) {
    int t = t0 + i;
    size_t eo = ((size_t)t * BB + b) * 3;
    float e = ef[eo + col] + eb[eo + col] + btj;
    int m = mk[t];
    float M0 = T0 + e, M1 = T1 + e, M2 = T2 + e;
    float r00 = __shfl(S0, base + 0), r01 = __shfl(S0, base + 1), r02 = __shfl(S0, base + 2);
    float r10 = __shfl(S1, base + 0), r11 = __shfl(S1, base + 1), r12 = __shfl(S1, base + 2);
    float r20 = __shfl(S2, base + 0), r21 = __shfl(S2, base + 1), r22 = __shfl(S2, base + 2);
    if (m != 0) {
      S0 = lse3(r00 + M0, r01 + M1, r02 + M2);
      S1 = lse3(r10 + M0, r11 + M1, r12 + M2);
      S2 = lse3(r20 + M0, r21 + M1, r22 + M2);
    }
  }
  if (jj < 3) {
    float* o = segM + ((size_t)b * 16 + ch) * 9;
    o[0 * 3 + jj] = S0;
    o[1 * 3 + jj] = S1;
    o[2 * 3 + jj] = S2;
  }
}

// ---------------- K5b: gold path score (parallel over t) ----------------
__global__ __launch_bounds__(64) void crf_num(
    const float* __restrict__ ef, const float* __restrict__ eb,
    const float* __restrict__ btag, const int* __restrict__ tags,
    const int* __restrict__ masks, const float* __restrict__ st,
    const float* __restrict__ et, const float* __restrict__ tr_,
    float* __restrict__ numb)
{
  int b = blockIdx.x;
  int lane = threadIdx.x;
  float T[9];
  #pragma unroll
  for (int i = 0; i < 9; ++i) T[i] = tr_[i];
  float b0 = btag[0], b1 = btag[1], b2 = btag[2];
  const int* tg = tags + (size_t)b * SS;
  const int* mk = masks + (size_t)b * SS;
  float part = 0.f;
  int cnt = 0;
  for (int t = lane; t < SS; t += 64) {
    int m = mk[t];
    cnt += (m != 0);
    if (t > 0 && m != 0) {
      int ct = tg[t], pv = tg[t - 1];
      size_t eo = ((size_t)t * BB + b) * 3;
      float bc = (ct == 0) ? b0 : ((ct == 1) ? b1 : b2);
      part += T[pv * 3 + ct] + ef[eo + ct] + eb[eo + ct] + bc;
    }
  }
  #pragma unroll
  for (int off = 32; off > 0; off >>= 1) {
    part += __shfl_xor(part, off);
    cnt += __shfl_xor(cnt, off);
  }
  if (lane == 0) {
    int tg0 = tg[0];
    float bc = (tg0 == 0) ? b0 : ((tg0 == 1) ? b1 : b2);
    float num = part + st[tg0] + ef[b * 3 + tg0] + eb[b * 3 + tg0] + bc;
    int last = tg[cnt - 1];
    num += et[last];
    numb[b] = num;
  }
}

// ---------------- K5c: combine chunks, partition, final NLL ----------------
__global__ __launch_bounds__(512) void crf_fin(
    const float* __restrict__ segM, const float* __restrict__ numb,
    const float* __restrict__ ef, const float* __restrict__ eb,
    const float* __restrict__ btag, const float* __restrict__ st,
    const float* __restrict__ et, float* __restrict__ out)
{
  int tid = threadIdx.x;
  int b = tid >> 4;
  int lane = tid & 63;
  int jj = tid & 15;
  int base = lane & 48;
  int col = (jj < 3) ? jj : 0;
  const float* sm = segM + (size_t)b * 16 * 9;
  float S0 = sm[0 * 3 + col], S1 = sm[1 * 3 + col], S2 = sm[2 * 3 + col];
  for (int ch = 1; ch < 16; ++ch) {
    float M0 = sm[ch * 9 + 0 * 3 + col];
    float M1 = sm[ch * 9 + 1 * 3 + col];
    float M2 = sm[ch * 9 + 2 * 3 + col];
    float r00 = __shfl(S0, base + 0), r01 = __shfl(S0, base + 1), r02 = __shfl(S0, base + 2);
    float r10 = __shfl(S1, base + 0), r11 = __shfl(S1, base + 1), r12 = __shfl(S1, base + 2);
    float r20 = __shfl(S2, base + 0), r21 = __shfl(S2, base + 1), r22 = __shfl(S2, base + 2);
    S0 = lse3(r00 + M0, r01 + M1, r02 + M2);
    S1 = lse3(r10 + M0, r11 + M1, r12 + M2);
    S2 = lse3(r20 + M0, r21 + M1, r22 + M2);
  }
  float A0 = st[0] + ef[b * 3 + 0] + eb[b * 3 + 0] + btag[0];
  float A1 = st[1] + ef[b * 3 + 1] + eb[b * 3 + 1] + btag[1];
  float A2 = st[2] + ef[b * 3 + 2] + eb[b * 3 + 2] + btag[2];
  float alpha = lse3(A0 + S0, A1 + S1, A2 + S2);   // column jj
  float v = alpha + et[col];
  float v0 = __shfl(v, base + 0), v1 = __shfl(v, base + 1), v2 = __shfl(v, base + 2);
  float den = lse3(v0, v1, v2);
  __shared__ float rbuf[32];
  if (jj == 0) rbuf[b] = numb[b] - den;
  __syncthreads();
  if (tid == 0) {
    float s = 0.f;
    #pragma unroll
    for (int i = 0; i < 32; ++i) s += rbuf[i];
    out[0] = -s;
  }
}

extern "C" void kernel_launch(void* const* d_in, const int* in_sizes, int n_in,
                              void* d_out, int out_size, void* d_ws, size_t ws_size,
                              hipStream_t stream) {
  const int* seq    = (const int*)d_in[0];
  const int* tags   = (const int*)d_in[1];
  const int* masks  = (const int*)d_in[2];
  const float* wemb = (const float*)d_in[3];
  const float* cemb = (const float*)d_in[4];
  const float* cWih = (const float*)d_in[5];
  const float* cb   = (const float*)d_in[6];
  const float* l0Wih = (const float*)d_in[7];
  const float* l0Whh = (const float*)d_in[8];
  const float* l0b   = (const float*)d_in[9];
  const float* l1Wih = (const float*)d_in[10];
  const float* l1Whh = (const float*)d_in[11];
  const float* l1b   = (const float*)d_in[12];
  const float* Wtag  = (const float*)d_in[13];
  const float* btag  = (const float*)d_in[14];
  const float* st    = (const float*)d_in[15];
  const float* et    = (const float*)d_in[16];
  const float* tr    = (const float*)d_in[17];
  float* outp = (float*)d_out;

  // ---- choose time-chunk Tc so the workspace fits ws_size ----
  const size_t fixed_fl = 4194304ull + 16777216ull + 393216ull + 16384ull + 8192ull;
  int Tc = 64;
  const int cands[6] = {2048, 1024, 512, 256, 128, 64};
  for (int i = 0; i < 6; ++i) {
    size_t need = (fixed_fl + (size_t)cands[i] * 40960ull) * 4ull;
    if (need <= ws_size || i == 5) { Tc = cands[i]; if (need <= ws_size) break; }
  }
  int nphase = SS / Tc;

  float* ws = (float*)d_ws;
  float* char_feat = ws;                              // 4,194,304
  float* xg      = char_feat + 4194304;               // Tc*32768
  float* h0      = xg + (size_t)Tc * 32768;           // 16,777,216
  float* h1c     = h0 + 16777216;                     // Tc*8192
  float* em_part = h1c + (size_t)Tc * 8192;           // 393,216
  float* hstate  = em_part + 393216;                  // 8,192
  float* cstate  = hstate + 8192;                     // 8,192
  float* segM    = cstate + 8192;                     // 4,608
  float* numb    = segM + 4608;                       // 32

  char_kernel<<<SBTOK * 64 / 256, 256, 0, stream>>>(seq, cemb, cWih, cb, char_feat);

  dim3 pg(Tc / 4, 16);
  // ---- layer 0 ----
  zero_kernel<<<64, 256, 0, stream>>>(hstate, 16384);
  for (int p = 0; p < nphase; ++p) {
    proj_seg<0, 192><<<pg, 256, 0, stream>>>(char_feat, seq, wemb, l0Wih, l0b, xg, Tc, p);
    scan_seg<0><<<64, 512, 0, stream>>>(xg, l0Whh, h0, hstate, cstate, Tc, p);
  }
  // ---- layer 1 ----
  zero_kernel<<<64, 256, 0, stream>>>(hstate, 16384);
  for (int p = 0; p < nphase; ++p) {
    proj_seg<1, 256><<<pg, 256, 0, stream>>>(h0, seq, wemb, l1Wih, l1b, xg, Tc, p);
    scan_seg<1><<<64, 512, 0, stream>>>(xg, l1Whh, h1c, hstate, cstate, Tc, p);
    emis_seg<<<Tc * 16, 256, 0, stream>>>(h1c, Wtag, em_part, Tc, p);
  }
  const float* ef = em_part;
  const float* eb = em_part + (size_t)SBTOK * 3;
  crf_seg<<<32, 256, 0, stream>>>(ef, eb, btag, (const float*)masks, nullptr, tr, segM);
  crf_num<<<32, 64, 0, stream>>>(ef, eb, btag, tags, masks, st, et, tr, numb);
  crf_fin<<<1, 512, 0, stream>>>(segM, numb, ef, eb, btag, st, et, outp);
}